// Round 4
// baseline (248.599 us; speedup 1.0000x reference)
//
#include <hip/hip_runtime.h>

// Problem constants
#define H_ 96
#define W_ 96
#define HW 9216        // 96*96
#define C_ 64
#define OUTC 64
#define NPTS 9         // N = KS*KS
#define NCH 18         // 2*N offset channels
#define B_ 8
#define NPIX 73728     // B*H*W

typedef __attribute__((ext_vector_type(8))) short short8;   // 8 bf16 = 4 VGPRs
typedef __attribute__((ext_vector_type(4))) float f32x4;

__device__ __forceinline__ short f2bf(float f) {
    union { float f; unsigned u; } v; v.f = f;
    unsigned r = v.u + 0x7fffu + ((v.u >> 16) & 1u);   // RNE
    return (short)(r >> 16);
}

// ---------------- Kernel A: offset field (3x3 conv, pad 1), c-split x4 ----------------
// XCD swizzle: b = blockIdx & 7 pins each batch image to one XCD's L2 (8 XCDs, 8 images).
__global__ __launch_bounds__(256) void offs_kernel(
    const float* __restrict__ x, const float* __restrict__ w_off,
    const float* __restrict__ b_off, float* __restrict__ offs)
{
    __shared__ float s_red[4 * NCH * 64];   // 18.4 KB
    int t  = threadIdx.x;
    int pl = t & 63;
    int cg = __builtin_amdgcn_readfirstlane(t >> 6);  // wave-uniform group id

    int b    = blockIdx.x & 7;          // image -> XCD pin
    int rem0 = (blockIdx.x >> 3) * 64;  // 144 tiles per image
    int pix  = rem0 + pl;
    int i    = pix / W_;
    int j    = pix - i * W_;

    float acc[NCH];
#pragma unroll
    for (int ch = 0; ch < NCH; ++ch) acc[ch] = 0.0f;

    for (int cl = 0; cl < 16; ++cl) {
        int c = cg * 16 + cl;
        const float* xp = x + (b * C_ + c) * HW;
        float v[9];
#pragma unroll
        for (int u = 0; u < 3; ++u)
#pragma unroll
            for (int vv = 0; vv < 3; ++vv) {
                int ii = i + u - 1, jj = j + vv - 1;
                bool ok = (ii >= 0) & (ii < H_) & (jj >= 0) & (jj < W_);
                v[u * 3 + vv] = ok ? xp[ii * W_ + jj] : 0.0f;
            }
        const float* wb = w_off + c * 9;   // wave-uniform -> s_load
#pragma unroll
        for (int ch = 0; ch < NCH; ++ch) {
#pragma unroll
            for (int uv = 0; uv < 9; ++uv)
                acc[ch] += v[uv] * wb[ch * (C_ * 9) + uv];
        }
    }

#pragma unroll
    for (int ch = 0; ch < NCH; ++ch) s_red[(cg * NCH + ch) * 64 + pl] = acc[ch];
    __syncthreads();

    for (int idx = t; idx < NCH * 64; idx += 256) {
        int ch = idx >> 6, p = idx & 63;
        float s = s_red[ch * 64 + p]
                + s_red[(NCH + ch) * 64 + p]
                + s_red[(2 * NCH + ch) * 64 + p]
                + s_red[(3 * NCH + ch) * 64 + p];
        offs[(b * NCH + ch) * HW + rem0 + p] = s + b_off[ch];
    }
}

// ---------------- Kernel T: w_ker -> bf16 B-fragment layout ----------------
// Frag storage: flat bf16 index = ((sg*4 + nt)*512) + l*8 + j,  sg = g*6+s in [0,18)
// Element = B[k][oc] with k_local = nl*64 + c, nl = s>>1, c = (s&1)*32 + (l>>4)*8 + j,
//           oc = nt*16 + (l&15), kernel tap n = g*3 + nl.
__global__ __launch_bounds__(256) void wk_frag_kernel(
    const float* __restrict__ w_ker, short* __restrict__ wk_frag)
{
    int idx = blockIdx.x * 256 + threadIdx.x;   // 144*256 = 36864 exactly
    int jj = idx & 7;
    int l  = (idx >> 3) & 63;
    int nt = (idx >> 9) & 3;
    int sg = idx >> 11;                // g*6 + s
    int g  = sg / 6;
    int s  = sg - g * 6;
    int nl = s >> 1;
    int c  = (s & 1) * 32 + (l >> 4) * 8 + jj;
    int oc = nt * 16 + (l & 15);
    wk_frag[idx] = f2bf(w_ker[(oc * C_ + c) * 9 + g * 3 + nl]);
}

// ---------------- Kernel B: fused bilinear sample + MFMA GEMM ----------------
// Block: 256 thr (4 waves), 64-px tile, all 64 oc, K=576 in 3 n-groups of 192.
// A staged in LDS in MFMA A-frag layout (bf16); B-frags read from global (L1-hot).
// XCD swizzle: b = blockIdx & 7 so each image's x + offs stay resident in one XCD L2.
__global__ __launch_bounds__(256, 4) void deform_mfma(
    const float* __restrict__ x, const float* __restrict__ offs,
    const short* __restrict__ wk_frag, const float* __restrict__ b_ker,
    float* __restrict__ out)
{
    // union: A-frag area (64px*192k bf16 = 24576 B)  /  out-stage (64*68 f32 = 17408 B)
    __shared__ __align__(16) char smem_raw[24576];
    short* sA   = (short*)smem_raw;
    float* sOut = (float*)smem_raw;

    int t    = threadIdx.x;
    int lane = t & 63;
    int wv   = t >> 6;          // wave id == m-tile  (also sampling c-group)
    int cg   = wv;

    int b    = blockIdx.x & 7;          // image -> XCD pin
    int rem0 = (blockIdx.x >> 3) * 64;  // 144 tiles per image
    int pxl  = t & 63;            // my pixel within tile (same for all 4 c-groups)
    int pix  = rem0 + pxl;
    int i    = pix / W_;
    int j    = pix - i * W_;

    const float* xb = x + b * C_ * HW;

    f32x4 acc[4];
#pragma unroll
    for (int nt = 0; nt < 4; ++nt) acc[nt] = (f32x4){0.f, 0.f, 0.f, 0.f};

    for (int g = 0; g < 3; ++g) {
        // ---- sample phase: 3 taps x 16 channels -> bf16 A-frags in LDS ----
#pragma unroll
        for (int nl = 0; nl < 3; ++nl) {
            int n = g * 3 + nl;
            float offx = offs[(b * NCH + n) * HW + pix];
            float offy = offs[(b * NCH + NPTS + n) * HW + pix];
            float px = (float)(i + g - 1) + offx;
            float py = (float)(j + nl - 1) + offy;
            float x0f = floorf(px), y0f = floorf(py);
            float lx = px - x0f, ly = py - y0f;
            int xi = (int)x0f, yi = (int)y0f;

            int a4[4]; float w4[4];
            float wx[2] = {1.0f - lx, lx};
            float wy[2] = {1.0f - ly, ly};
#pragma unroll
            for (int q = 0; q < 4; ++q) {
                int cx = xi + (q & 1);
                int cy = yi + (q >> 1);
                bool ok = (cx >= 0) & (cx < H_) & (cy >= 0) & (cy < W_);
                int ax = min(max(cx, 0), H_ - 1);
                int ay = min(max(cy, 0), W_ - 1);
                a4[q] = ax * W_ + ay;
                w4[q] = ok ? wx[q & 1] * wy[q >> 1] : 0.0f;
            }

            int s = nl * 2 + (cg >> 1);            // local k-step
#pragma unroll
            for (int q2 = 0; q2 < 2; ++q2) {
                int l = (pxl & 15) | (((cg & 1) * 2 + q2) << 4);
                short8 pk;
#pragma unroll
                for (int e = 0; e < 8; ++e) {
                    int c = cg * 16 + q2 * 8 + e;
                    const float* xp = xb + c * HW;
                    float v = w4[0] * xp[a4[0]] + w4[1] * xp[a4[1]]
                            + w4[2] * xp[a4[2]] + w4[3] * xp[a4[3]];
                    pk[e] = f2bf(v);
                }
                *(short8*)(&sA[(((pxl >> 4) * 6 + s) << 9) + l * 8]) = pk;
            }
        }
        __syncthreads();
        // ---- MFMA phase: 6 k-steps x 4 oc-tiles ----
#pragma unroll
        for (int s = 0; s < 6; ++s) {
            short8 a = *(const short8*)(&sA[((wv * 6 + s) << 9) + lane * 8]);
            const short* wb = wk_frag + (((g * 6 + s) * 4) << 9) + lane * 8;
#pragma unroll
            for (int nt = 0; nt < 4; ++nt) {
                short8 bf = *(const short8*)(wb + (nt << 9));
                acc[nt] = __builtin_amdgcn_mfma_f32_16x16x32_bf16(a, bf, acc[nt], 0, 0, 0);
            }
        }
        __syncthreads();   // protect sA before next group's sampler (and sOut reuse)
    }

    // ---- epilogue: C-frags -> padded LDS -> coalesced float4 stores ----
    int colc = lane & 15, rowq = lane >> 4;
#pragma unroll
    for (int nt = 0; nt < 4; ++nt) {
        int oc = nt * 16 + colc;
        float bias = b_ker[oc];
#pragma unroll
        for (int r = 0; r < 4; ++r) {
            int p = wv * 16 + rowq * 4 + r;     // C/D: col=lane&15, row=(lane>>4)*4+reg
            sOut[p * 68 + oc] = acc[nt][r] + bias;
        }
    }
    __syncthreads();

    int oc = t >> 2, pq = t & 3;
    float* op = out + (b * OUTC + oc) * HW + rem0;
#pragma unroll
    for (int e2 = 0; e2 < 4; ++e2) {
        int p0 = pq * 4 + e2 * 16;
        float4 v = make_float4(sOut[(p0 + 0) * 68 + oc], sOut[(p0 + 1) * 68 + oc],
                               sOut[(p0 + 2) * 68 + oc], sOut[(p0 + 3) * 68 + oc]);
        *(float4*)(op + p0) = v;
    }
}

extern "C" void kernel_launch(void* const* d_in, const int* in_sizes, int n_in,
                              void* d_out, int out_size, void* d_ws, size_t ws_size,
                              hipStream_t stream) {
    const float* x     = (const float*)d_in[0];
    const float* w_off = (const float*)d_in[1];
    const float* b_off = (const float*)d_in[2];
    const float* w_ker = (const float*)d_in[3];
    const float* b_ker = (const float*)d_in[4];
    float* out = (float*)d_out;

    float* ws      = (float*)d_ws;
    float* offs    = ws;                        // 1,327,104 floats (5.3 MB)
    short* wk_frag = (short*)(ws + 1327104);    // 36,864 bf16 (72 KB)

    offs_kernel   <<<NPIX / 64, 256, 0, stream>>>(x, w_off, b_off, offs);
    wk_frag_kernel<<<144,       256, 0, stream>>>(w_ker, wk_frag);
    deform_mfma   <<<NPIX / 64, 256, 0, stream>>>(x, offs, wk_frag, b_ker, out);
}

// Round 5
// 152.371 us; speedup vs baseline: 1.6315x; 1.6315x over previous
//
#include <hip/hip_runtime.h>

// Problem constants
#define H_ 96
#define W_ 96
#define HW 9216        // 96*96
#define C_ 64
#define OUTC 64
#define NPTS 9
#define NCH 18
#define B_ 8
#define NPIX 73728     // B*H*W

typedef __attribute__((ext_vector_type(8))) short short8;   // 8 bf16
typedef __attribute__((ext_vector_type(4))) float f32x4;
typedef __attribute__((ext_vector_type(4))) unsigned int uint4v;

__device__ __forceinline__ short f2bf(float f) {
    union { float f; unsigned u; } v; v.f = f;
    unsigned r = v.u + 0x7fffu + ((v.u >> 16) & 1u);   // RNE
    return (short)(r >> 16);
}
__device__ __forceinline__ float bflo(unsigned d) {   // low bf16 of dword -> f32
    union { unsigned u; float f; } v; v.u = d << 16; return v.f;
}
__device__ __forceinline__ float bfhi(unsigned d) {   // high bf16 of dword -> f32
    union { unsigned u; float f; } v; v.u = d & 0xffff0000u; return v.f;
}

// ---------------- Kernel 1: x (B,C,H,W) f32 -> x_t (B,HW,C) bf16 ----------------
// Thread owns an 8px x 8ch tile: coalesced float4 reads, coalesced short8 writes.
__global__ __launch_bounds__(256) void xpose_kernel(
    const float* __restrict__ x, short* __restrict__ x_t)
{
    int b   = blockIdx.x & 7;          // image -> XCD pin
    int sub = blockIdx.x >> 3;         // 0..35
    int t   = threadIdx.x;
    int cb  = t & 7;                   // channel block (8 ch)
    int pix = (sub * 32 + (t >> 3)) * 8;

    const float* xp  = x   + ((size_t)(b * C_ + cb * 8) * HW) + pix;
    short*       opq = x_t + ((size_t)(b * HW + pix) * 64) + cb * 8;

    float tile[8][8];   // [ch][px]
#pragma unroll
    for (int e = 0; e < 8; ++e) {
        f32x4 a0 = *(const f32x4*)(xp + (size_t)e * HW);
        f32x4 a1 = *(const f32x4*)(xp + (size_t)e * HW + 4);
#pragma unroll
        for (int p = 0; p < 4; ++p) { tile[e][p] = a0[p]; tile[e][4 + p] = a1[p]; }
    }
#pragma unroll
    for (int p = 0; p < 8; ++p) {
        short8 v;
#pragma unroll
        for (int e = 0; e < 8; ++e) v[e] = f2bf(tile[e][p]);
        *(short8*)(opq + p * 64) = v;
    }
}

// ---------------- Kernel 2: weight fragments (w_ker + w_off) ----------------
// B-frag layout (validated in R3/R4): flat = (sg*NT + nt)*512 + l*8 + j
//   sg = n*2 + q2 (tap n, 32-ch half q2); c = q2*32 + (l>>4)*8 + j; oc = nt*16 + (l&15)
__global__ __launch_bounds__(256) void prep_kernel(
    const float* __restrict__ w_ker, const float* __restrict__ w_off,
    short* __restrict__ wk_frag, short* __restrict__ woff_frag)
{
    int idx = blockIdx.x * 256 + threadIdx.x;   // 216*256 = 55296
    if (idx < 36864) {                          // wk_frag: NT=4
        int j = idx & 7, l = (idx >> 3) & 63, nt = (idx >> 9) & 3, sg = idx >> 11;
        int q2 = sg & 1, n = sg >> 1;
        int c  = q2 * 32 + ((l >> 4) << 3) + j;
        int oc = nt * 16 + (l & 15);
        wk_frag[idx] = f2bf(w_ker[(oc * C_ + c) * 9 + n]);
    } else {                                    // woff_frag: NT=2 (N padded 18->32)
        int k = idx - 36864;                    // 0..18431
        int j = k & 7, l = (k >> 3) & 63, nt = (k >> 9) & 1, sg = k >> 10;
        int q2 = sg & 1, n = sg >> 1;
        int c  = q2 * 32 + ((l >> 4) << 3) + j;
        int oc = nt * 16 + (l & 15);
        woff_frag[k] = (oc < NCH) ? f2bf(w_off[(oc * C_ + c) * 9 + n]) : (short)0;
    }
}

// ---------------- Kernel 3: offset conv via MFMA ----------------
// 1 wave = 16 px x 18(32) offset channels, K=576. Stencil A-frags from x_t, zero pad.
// Output: offs_pairs[(b*HW+pix)*9 + n] = float2(offx_n, offy_n).
__global__ __launch_bounds__(64, 4) void offs_mfma(
    const short* __restrict__ x_t, const short* __restrict__ woff_frag,
    const float* __restrict__ b_off, float* __restrict__ offs_pairs)
{
    __shared__ float sO[16 * 20];
    int lane = threadIdx.x;
    int b    = blockIdx.x & 7;           // image -> XCD pin
    int px0  = (blockIdx.x >> 3) * 16;   // 576 strips per image
    int pxl  = lane & 15, kq = lane >> 4;
    int pix  = px0 + pxl;
    int i = pix / W_, j = pix - i * W_;
    const short* xb = x_t + (size_t)b * HW * 64;
    const short8 Z8 = {0,0,0,0,0,0,0,0};

    f32x4 acc0 = {0,0,0,0}, acc1 = {0,0,0,0};
#pragma unroll
    for (int n = 0; n < 9; ++n) {
        int di = n / 3 - 1, dj = n % 3 - 1;
        int ii = i + di, jj = j + dj;
        bool ok = (ii >= 0) & (ii < H_) & (jj >= 0) & (jj < W_);
        int cp = min(max(ii, 0), H_ - 1) * W_ + min(max(jj, 0), W_ - 1);
        const short* ap = xb + cp * 64 + kq * 8;
#pragma unroll
        for (int q2 = 0; q2 < 2; ++q2) {
            short8 a = *(const short8*)(ap + q2 * 32);
            a = ok ? a : Z8;
            const short* wb = woff_frag + ((n * 2 + q2) * 2) * 512 + lane * 8;
            short8 b0 = *(const short8*)(wb);
            short8 b1 = *(const short8*)(wb + 512);
            acc0 = __builtin_amdgcn_mfma_f32_16x16x32_bf16(a, b0, acc0, 0, 0, 0);
            acc1 = __builtin_amdgcn_mfma_f32_16x16x32_bf16(a, b1, acc1, 0, 0, 0);
        }
    }
    // C/D: col=lane&15 (=ch), row=(lane>>4)*4+r (=px). Stage to LDS then pair-store.
    int col = lane & 15, rq = lane >> 4;
    float bo0 = b_off[col];
#pragma unroll
    for (int r = 0; r < 4; ++r)
        sO[(rq * 4 + r) * 20 + col] = acc0[r] + bo0;
    if (col < 2) {
        float bo1 = b_off[16 + col];
#pragma unroll
        for (int r = 0; r < 4; ++r)
            sO[(rq * 4 + r) * 20 + 16 + col] = acc1[r] + bo1;
    }
    __syncthreads();
#pragma unroll
    for (int rep = 0; rep < 3; ++rep) {
        int idx = rep * 64 + lane;
        if (idx < 144) {
            int p = idx / 9, n = idx - p * 9;
            float2 v = make_float2(sO[p * 20 + n], sO[p * 20 + 9 + n]);
            *(float2*)&offs_pairs[((size_t)(b * HW + px0 + p) * 9 + n) * 2] = v;
        }
    }
}

// ---------------- Kernel 4: deformable sample + MFMA GEMM, register A-frags ----------------
// 1 wave = 16 px x 64 oc, K=576. Lane = (px, 8ch-group): 4 corner loads of 16B per
// k-step, interp in f32, pack to bf16 A-frag, MFMA. No barriers in the K-loop.
__global__ __launch_bounds__(64, 4) void deform_mfma(
    const short* __restrict__ x_t, const float* __restrict__ offs_pairs,
    const short* __restrict__ wk_frag, const float* __restrict__ b_ker,
    float* __restrict__ out)
{
    __shared__ float sE[64 * 20];
    int lane = threadIdx.x;
    int b    = blockIdx.x & 7;           // image -> XCD pin
    int px0  = (blockIdx.x >> 3) * 16;
    int pxl  = lane & 15, kq = lane >> 4;
    int pix  = px0 + pxl;
    int i = pix / W_, j = pix - i * W_;
    const short* xb = x_t + (size_t)b * HW * 64;
    const float* op = offs_pairs + (size_t)(b * HW + pix) * 18;

    f32x4 acc[4];
#pragma unroll
    for (int nt = 0; nt < 4; ++nt) acc[nt] = (f32x4){0.f, 0.f, 0.f, 0.f};

#pragma unroll
    for (int n = 0; n < 9; ++n) {
        float2 o = *(const float2*)(op + n * 2);
        float fpx = (float)(i + n / 3 - 1) + o.x;
        float fpy = (float)(j + n % 3 - 1) + o.y;
        float x0f = floorf(fpx), y0f = floorf(fpy);
        float lx = fpx - x0f, ly = fpy - y0f;
        int xi = (int)x0f, yi = (int)y0f;
        // factored validity: zero the 1-D weights for OOB rows/cols
        float wx0 = (xi >= 0  && xi <= H_ - 1) ? (1.0f - lx) : 0.0f;
        float wx1 = (xi >= -1 && xi <= H_ - 2) ? lx          : 0.0f;
        float wy0 = (yi >= 0  && yi <= W_ - 1) ? (1.0f - ly) : 0.0f;
        float wy1 = (yi >= -1 && yi <= W_ - 2) ? ly          : 0.0f;
        float w00 = wx0 * wy0, w10 = wx1 * wy0, w01 = wx0 * wy1, w11 = wx1 * wy1;
        int r0 = min(max(xi,     0), H_ - 1) * W_;
        int r1 = min(max(xi + 1, 0), H_ - 1) * W_;
        int c0 = min(max(yi,     0), W_ - 1);
        int c1 = min(max(yi + 1, 0), W_ - 1);
        const short* p00 = xb + (r0 + c0) * 64 + kq * 8;
        const short* p10 = xb + (r1 + c0) * 64 + kq * 8;
        const short* p01 = xb + (r0 + c1) * 64 + kq * 8;
        const short* p11 = xb + (r1 + c1) * 64 + kq * 8;
#pragma unroll
        for (int q2 = 0; q2 < 2; ++q2) {
            uint4v u0 = *(const uint4v*)(p00 + q2 * 32);
            uint4v u1 = *(const uint4v*)(p10 + q2 * 32);
            uint4v u2 = *(const uint4v*)(p01 + q2 * 32);
            uint4v u3 = *(const uint4v*)(p11 + q2 * 32);
            short8 A;
#pragma unroll
            for (int d = 0; d < 4; ++d) {
                float lo = w00 * bflo(u0[d]) + w10 * bflo(u1[d])
                         + w01 * bflo(u2[d]) + w11 * bflo(u3[d]);
                float hi = w00 * bfhi(u0[d]) + w10 * bfhi(u1[d])
                         + w01 * bfhi(u2[d]) + w11 * bfhi(u3[d]);
                A[2 * d]     = f2bf(lo);
                A[2 * d + 1] = f2bf(hi);
            }
            const short* wbp = wk_frag + ((n * 2 + q2) * 4) * 512 + lane * 8;
#pragma unroll
            for (int nt = 0; nt < 4; ++nt) {
                short8 bfr = *(const short8*)(wbp + nt * 512);
                acc[nt] = __builtin_amdgcn_mfma_f32_16x16x32_bf16(A, bfr, acc[nt], 0, 0, 0);
            }
        }
    }

    // epilogue: C-frags -> LDS[oc][px] (stride 20 keeps 16B align) -> 4 coalesced f32x4
    int col = lane & 15, rq = lane >> 4;
#pragma unroll
    for (int nt = 0; nt < 4; ++nt) {
        int oc = nt * 16 + col;
        float bias = b_ker[oc];
#pragma unroll
        for (int r = 0; r < 4; ++r)
            sE[oc * 20 + rq * 4 + r] = acc[nt][r] + bias;
    }
    __syncthreads();
    float* outp = out + ((size_t)(b * OUTC + lane) * HW) + px0;   // lane = oc
#pragma unroll
    for (int s = 0; s < 4; ++s) {
        f32x4 v = *(const f32x4*)&sE[lane * 20 + s * 4];
        *(f32x4*)(outp + s * 4) = v;
    }
}

extern "C" void kernel_launch(void* const* d_in, const int* in_sizes, int n_in,
                              void* d_out, int out_size, void* d_ws, size_t ws_size,
                              hipStream_t stream) {
    const float* x     = (const float*)d_in[0];
    const float* w_off = (const float*)d_in[1];
    const float* b_off = (const float*)d_in[2];
    const float* w_ker = (const float*)d_in[3];
    const float* b_ker = (const float*)d_in[4];
    float* out = (float*)d_out;

    // workspace layout (~14.3 MB)
    char*  wsb        = (char*)d_ws;
    short* x_t        = (short*)wsb;                       // 4,718,592 sh = 9,437,184 B
    float* offs_pairs = (float*)(wsb + 9437184);           // 1,327,104 f  = 5,308,416 B
    short* wk_frag    = (short*)(wsb + 9437184 + 5308416); // 36,864 sh    =    73,728 B
    short* woff_frag  = wk_frag + 36864;                   // 18,432 sh    =    36,864 B

    xpose_kernel<<<288,  256, 0, stream>>>(x, x_t);
    prep_kernel <<<216,  256, 0, stream>>>(w_ker, w_off, wk_frag, woff_frag);
    offs_mfma   <<<4608,  64, 0, stream>>>(x_t, woff_frag, b_off, offs_pairs);
    deform_mfma <<<4608,  64, 0, stream>>>(x_t, offs_pairs, wk_frag, b_ker, out);
}

// Round 6
// 143.339 us; speedup vs baseline: 1.7343x; 1.0630x over previous
//
#include <hip/hip_runtime.h>

// Problem constants
#define H_ 96
#define W_ 96
#define HW 9216        // 96*96
#define C_ 64
#define OUTC 64
#define NPTS 9
#define NCH 18
#define B_ 8
#define NPIX 73728     // B*H*W

typedef __attribute__((ext_vector_type(8))) short short8;   // 8 bf16
typedef __attribute__((ext_vector_type(4))) float f32x4;
typedef __attribute__((ext_vector_type(4))) unsigned int uint4v;

__device__ __forceinline__ short f2bf(float f) {
    union { float f; unsigned u; } v; v.f = f;
    unsigned r = v.u + 0x7fffu + ((v.u >> 16) & 1u);   // RNE
    return (short)(r >> 16);
}
__device__ __forceinline__ float bflo(unsigned d) {
    union { unsigned u; float f; } v; v.u = d << 16; return v.f;
}
__device__ __forceinline__ float bfhi(unsigned d) {
    union { unsigned u; float f; } v; v.u = d & 0xffff0000u; return v.f;
}

// ---------------- Kernel 1: fused transpose + weight prep ----------------
// blocks 0..287: x (B,C,H,W) f32 -> x_t (B,HW,C) bf16 (XCD-pinned per image)
// blocks 288..503: w_ker/w_off -> MFMA B-fragment layouts
__global__ __launch_bounds__(256) void prep_xpose(
    const float* __restrict__ x, const float* __restrict__ w_ker,
    const float* __restrict__ w_off, short* __restrict__ x_t,
    short* __restrict__ wk_frag, short* __restrict__ woff_frag)
{
    int blk = blockIdx.x;
    int t   = threadIdx.x;
    if (blk < 288) {
        int b   = blk & 7;              // image -> XCD pin
        int sub = blk >> 3;             // 0..35
        int cb  = t & 7;                // 8-channel block
        int pix = (sub * 32 + (t >> 3)) * 8;

        const float* xp  = x   + ((size_t)(b * C_ + cb * 8) * HW) + pix;
        short*       opq = x_t + ((size_t)(b * HW + pix) * 64) + cb * 8;

        float tile[8][8];   // [ch][px]
#pragma unroll
        for (int e = 0; e < 8; ++e) {
            f32x4 a0 = *(const f32x4*)(xp + (size_t)e * HW);
            f32x4 a1 = *(const f32x4*)(xp + (size_t)e * HW + 4);
#pragma unroll
            for (int p = 0; p < 4; ++p) { tile[e][p] = a0[p]; tile[e][4 + p] = a1[p]; }
        }
#pragma unroll
        for (int p = 0; p < 8; ++p) {
            short8 v;
#pragma unroll
            for (int e = 0; e < 8; ++e) v[e] = f2bf(tile[e][p]);
            *(short8*)(opq + p * 64) = v;
        }
    } else {
        int idx = (blk - 288) * 256 + t;            // 0..55295
        if (idx < 36864) {                          // wk_frag: NT=4
            int j = idx & 7, l = (idx >> 3) & 63, nt = (idx >> 9) & 3, sg = idx >> 11;
            int q2 = sg & 1, n = sg >> 1;
            int c  = q2 * 32 + ((l >> 4) << 3) + j;
            int oc = nt * 16 + (l & 15);
            wk_frag[idx] = f2bf(w_ker[(oc * C_ + c) * 9 + n]);
        } else {                                    // woff_frag: NT=2 (18 padded to 32)
            int k = idx - 36864;                    // 0..18431
            int j = k & 7, l = (k >> 3) & 63, nt = (k >> 9) & 1, sg = k >> 10;
            int q2 = sg & 1, n = sg >> 1;
            int c  = q2 * 32 + ((l >> 4) << 3) + j;
            int oc = nt * 16 + (l & 15);
            woff_frag[k] = (oc < NCH) ? f2bf(w_off[(oc * C_ + c) * 9 + n]) : (short)0;
        }
    }
}

// ---------------- Kernel 2: fused offset-conv + deformable sample + GEMM ----------------
// Block = 128 thr (2 waves) = 16 px of one image. Phase 1: offset conv via MFMA,
// taps split 5/4 across waves, partials reduced in LDS -> per-pixel (ox,oy) table.
// Phase 2: bilinear sample (register A-frags) + MFMA GEMM, taps split 4/5,
// accumulators reduced in LDS epilogue. No global offset buffer.
__global__ __launch_bounds__(128, 4) void deform_fused(
    const short* __restrict__ x_t, const short* __restrict__ woff_frag,
    const float* __restrict__ b_off, const short* __restrict__ wk_frag,
    const float* __restrict__ b_ker, float* __restrict__ out)
{
    __shared__ float  sE[64 * 20];     // 5120 B; rows 0..31 double as phase-1 partials
    __shared__ float2 sP[16 * 9];      // per-pixel (ox,oy) per tap, 1152 B

    int t    = threadIdx.x;
    int lane = t & 63;
    int wv   = t >> 6;
    int b    = blockIdx.x & 7;          // image -> XCD pin
    int px0  = (blockIdx.x >> 3) * 16;  // 576 strips per image
    int pxl  = lane & 15, kq = lane >> 4;
    int pix  = px0 + pxl;
    int i = pix / W_, j = pix - i * W_;
    const short* xb = x_t + (size_t)b * HW * 64;
    const short8 Z8 = {0,0,0,0,0,0,0,0};

    // ---- phase 1: offset conv. wave0: taps 0-4, wave1: taps 5-8 ----
    {
        f32x4 a0 = {0,0,0,0}, a1 = {0,0,0,0};
        int nbase = wv ? 5 : 0;
        int ncnt  = wv ? 4 : 5;
#pragma unroll
        for (int q = 0; q < 5; ++q) {
            if (q < ncnt) {
                int n  = nbase + q;
                int ii = i + n / 3 - 1, jj = j + n % 3 - 1;
                bool ok = (ii >= 0) & (ii < H_) & (jj >= 0) & (jj < W_);
                int cp = min(max(ii, 0), H_ - 1) * W_ + min(max(jj, 0), W_ - 1);
                const short* ap = xb + cp * 64 + kq * 8;
#pragma unroll
                for (int q2 = 0; q2 < 2; ++q2) {
                    short8 a = *(const short8*)(ap + q2 * 32);
                    a = ok ? a : Z8;
                    const short* wb = woff_frag + ((n * 2 + q2) * 2) * 512 + lane * 8;
                    short8 b0 = *(const short8*)(wb);
                    short8 b1 = *(const short8*)(wb + 512);
                    a0 = __builtin_amdgcn_mfma_f32_16x16x32_bf16(a, b0, a0, 0, 0, 0);
                    a1 = __builtin_amdgcn_mfma_f32_16x16x32_bf16(a, b1, a1, 0, 0, 0);
                }
            }
        }
        // partials -> LDS: C/D col=lane&15 (=ch), row=(lane>>4)*4+r (=px)
        int col = lane & 15, rq = lane >> 4;
#pragma unroll
        for (int r = 0; r < 4; ++r)
            sE[(wv * 16 + rq * 4 + r) * 20 + col] = a0[r];
        if (col < 2) {
#pragma unroll
            for (int r = 0; r < 4; ++r)
                sE[(wv * 16 + rq * 4 + r) * 20 + 16 + col] = a1[r];
        }
    }
    __syncthreads();

    // ---- reduce partials + bias -> per-pixel offset pair table ----
#pragma unroll
    for (int s = 0; s < 2; ++s) {
        int idx = s * 128 + t;
        if (idx < 144) {
            int p = idx / 9, n = idx - p * 9;
            float ox = sE[p * 20 + n]     + sE[(16 + p) * 20 + n]     + b_off[n];
            float oy = sE[p * 20 + 9 + n] + sE[(16 + p) * 20 + 9 + n] + b_off[9 + n];
            sP[p * 9 + n] = make_float2(ox, oy);
        }
    }
    __syncthreads();

    // ---- phase 2: sample + GEMM. wave0: taps 0-3, wave1: taps 4-8 ----
    f32x4 acc[4];
#pragma unroll
    for (int nt = 0; nt < 4; ++nt) acc[nt] = (f32x4){0.f, 0.f, 0.f, 0.f};
    {
        int nbase = wv ? 4 : 0;
        int ncnt  = wv ? 5 : 4;
#pragma unroll
        for (int q = 0; q < 5; ++q) {
            if (q < ncnt) {
                int n = nbase + q;
                float2 o = sP[pxl * 9 + n];
                float fpx = (float)(i + n / 3 - 1) + o.x;
                float fpy = (float)(j + n % 3 - 1) + o.y;
                float x0f = floorf(fpx), y0f = floorf(fpy);
                float lx = fpx - x0f, ly = fpy - y0f;
                int xi = (int)x0f, yi = (int)y0f;
                float wx0 = (xi >= 0  && xi <= H_ - 1) ? (1.0f - lx) : 0.0f;
                float wx1 = (xi >= -1 && xi <= H_ - 2) ? lx          : 0.0f;
                float wy0 = (yi >= 0  && yi <= W_ - 1) ? (1.0f - ly) : 0.0f;
                float wy1 = (yi >= -1 && yi <= W_ - 2) ? ly          : 0.0f;
                float w00 = wx0 * wy0, w10 = wx1 * wy0, w01 = wx0 * wy1, w11 = wx1 * wy1;
                int r0 = min(max(xi,     0), H_ - 1) * W_;
                int r1 = min(max(xi + 1, 0), H_ - 1) * W_;
                int c0 = min(max(yi,     0), W_ - 1);
                int c1 = min(max(yi + 1, 0), W_ - 1);
                const short* p00 = xb + (r0 + c0) * 64 + kq * 8;
                const short* p10 = xb + (r1 + c0) * 64 + kq * 8;
                const short* p01 = xb + (r0 + c1) * 64 + kq * 8;
                const short* p11 = xb + (r1 + c1) * 64 + kq * 8;
#pragma unroll
                for (int q2 = 0; q2 < 2; ++q2) {
                    uint4v u0 = *(const uint4v*)(p00 + q2 * 32);
                    uint4v u1 = *(const uint4v*)(p10 + q2 * 32);
                    uint4v u2 = *(const uint4v*)(p01 + q2 * 32);
                    uint4v u3 = *(const uint4v*)(p11 + q2 * 32);
                    short8 A;
#pragma unroll
                    for (int d = 0; d < 4; ++d) {
                        float lo = w00 * bflo(u0[d]) + w10 * bflo(u1[d])
                                 + w01 * bflo(u2[d]) + w11 * bflo(u3[d]);
                        float hi = w00 * bfhi(u0[d]) + w10 * bfhi(u1[d])
                                 + w01 * bfhi(u2[d]) + w11 * bfhi(u3[d]);
                        A[2 * d]     = f2bf(lo);
                        A[2 * d + 1] = f2bf(hi);
                    }
                    const short* wbp = wk_frag + ((n * 2 + q2) * 4) * 512 + lane * 8;
#pragma unroll
                    for (int nt = 0; nt < 4; ++nt) {
                        short8 bfr = *(const short8*)(wbp + nt * 512);
                        acc[nt] = __builtin_amdgcn_mfma_f32_16x16x32_bf16(A, bfr, acc[nt], 0, 0, 0);
                    }
                }
            }
        }
    }

    // ---- epilogue: cross-wave reduce in LDS, then coalesced stores ----
    __syncthreads();   // all sP reads done; sE region free for reuse
    int col = lane & 15, rq = lane >> 4;
    if (wv == 0) {
#pragma unroll
        for (int nt = 0; nt < 4; ++nt) {
            int oc = nt * 16 + col;
            float bias = b_ker[oc];
#pragma unroll
            for (int r = 0; r < 4; ++r)
                sE[oc * 20 + rq * 4 + r] = acc[nt][r] + bias;
        }
    }
    __syncthreads();
    if (wv == 1) {
#pragma unroll
        for (int nt = 0; nt < 4; ++nt) {
            int oc = nt * 16 + col;
#pragma unroll
            for (int r = 0; r < 4; ++r)
                sE[oc * 20 + rq * 4 + r] += acc[nt][r];
        }
    }
    __syncthreads();

    int oc = t >> 1, half = t & 1;
    const float* se = &sE[oc * 20 + half * 8];
    float* outp = out + ((size_t)(b * OUTC + oc) * HW) + px0 + half * 8;
    *(f32x4*)outp       = *(const f32x4*)se;
    *(f32x4*)(outp + 4) = *(const f32x4*)(se + 4);
}

extern "C" void kernel_launch(void* const* d_in, const int* in_sizes, int n_in,
                              void* d_out, int out_size, void* d_ws, size_t ws_size,
                              hipStream_t stream) {
    const float* x     = (const float*)d_in[0];
    const float* w_off = (const float*)d_in[1];
    const float* b_off = (const float*)d_in[2];
    const float* w_ker = (const float*)d_in[3];
    const float* b_ker = (const float*)d_in[4];
    float* out = (float*)d_out;

    // workspace: x_t 9,437,184 B | wk_frag 73,728 B | woff_frag 36,864 B
    char*  wsb       = (char*)d_ws;
    short* x_t       = (short*)wsb;
    short* wk_frag   = (short*)(wsb + 9437184);
    short* woff_frag = wk_frag + 36864;

    prep_xpose  <<<504,  256, 0, stream>>>(x, w_ker, w_off, x_t, wk_frag, woff_frag);
    deform_fused<<<4608, 128, 0, stream>>>(x_t, woff_frag, b_off, wk_frag, b_ker, out);
}

// Round 7
// 113.933 us; speedup vs baseline: 2.1820x; 1.2581x over previous
//
#include <hip/hip_runtime.h>

// Problem constants
#define H_ 96
#define W_ 96
#define HW 9216        // 96*96
#define C_ 64
#define OUTC 64
#define NPTS 9
#define NCH 18
#define B_ 8
#define NPIX 73728     // B*H*W

// LDS patch: 5 rows x 20 cols x 64 ch (padded to 72 shorts) per 16-px strip
#define PCH 72

typedef __attribute__((ext_vector_type(8))) short short8;   // 8 bf16
typedef __attribute__((ext_vector_type(4))) float f32x4;
typedef __attribute__((ext_vector_type(4))) unsigned int uint4v;

__device__ __forceinline__ short f2bf(float f) {
    union { float f; unsigned u; } v; v.f = f;
    unsigned r = v.u + 0x7fffu + ((v.u >> 16) & 1u);   // RNE
    return (short)(r >> 16);
}
__device__ __forceinline__ float bflo(unsigned d) {
    union { unsigned u; float f; } v; v.u = d << 16; return v.f;
}
__device__ __forceinline__ float bfhi(unsigned d) {
    union { unsigned u; float f; } v; v.u = d & 0xffff0000u; return v.f;
}

// ---------------- Kernel 1: transpose (2px x 8ch per thread) + weight prep ----------------
__global__ __launch_bounds__(256) void prep_xpose(
    const float* __restrict__ x, const float* __restrict__ w_ker,
    const float* __restrict__ w_off, short* __restrict__ x_t,
    short* __restrict__ wk_frag, short* __restrict__ woff_frag)
{
    int blk = blockIdx.x;
    int t   = threadIdx.x;
    if (blk < 1152) {
        int b   = blk & 7;               // image -> XCD pin
        int sub = blk >> 3;              // 0..143
        int cb  = t & 7;                 // 8-channel block
        int pix = (sub * 32 + (t >> 3)) * 2;

        const float* xp = x + ((size_t)(b * C_ + cb * 8) * HW) + pix;
        float tl[8][2];
#pragma unroll
        for (int e = 0; e < 8; ++e) {
            float2 v = *(const float2*)(xp + (size_t)e * HW);
            tl[e][0] = v.x; tl[e][1] = v.y;
        }
#pragma unroll
        for (int p = 0; p < 2; ++p) {
            short8 s;
#pragma unroll
            for (int e = 0; e < 8; ++e) s[e] = f2bf(tl[e][p]);
            *(short8*)(x_t + ((size_t)(b * HW + pix + p) * 64) + cb * 8) = s;
        }
    } else {
        int idx = (blk - 1152) * 256 + t;           // 0..55295
        if (idx < 36864) {                          // wk_frag: NT=4
            int j = idx & 7, l = (idx >> 3) & 63, nt = (idx >> 9) & 3, sg = idx >> 11;
            int q2 = sg & 1, n = sg >> 1;
            int c  = q2 * 32 + ((l >> 4) << 3) + j;
            int oc = nt * 16 + (l & 15);
            wk_frag[idx] = f2bf(w_ker[(oc * C_ + c) * 9 + n]);
        } else {                                    // woff_frag: NT=2 (18 padded to 32)
            int k = idx - 36864;                    // 0..18431
            int j = k & 7, l = (k >> 3) & 63, nt = (k >> 9) & 1, sg = k >> 10;
            int q2 = sg & 1, n = sg >> 1;
            int c  = q2 * 32 + ((l >> 4) << 3) + j;
            int oc = nt * 16 + (l & 15);
            woff_frag[k] = (oc < NCH) ? f2bf(w_off[(oc * C_ + c) * 9 + n]) : (short)0;
        }
    }
}

// ---------------- Kernel 2: fused offset-conv + deformable sample + GEMM ----------------
// Block = 128 thr (2 waves) = 16-px strip. LDS patch (5x20x64ch) staged once,
// serves phase-1 stencil A-frags AND phase-2 bilinear corners (global fallback
// for the rare |offset|>=1 lane). Taps split across the 2 waves, LDS reductions.
__global__ __launch_bounds__(128, 3) void deform_fused(
    const short* __restrict__ x_t, const short* __restrict__ woff_frag,
    const float* __restrict__ b_off, const short* __restrict__ wk_frag,
    const float* __restrict__ b_ker, float* __restrict__ out)
{
    __shared__ short  sX[100 * PCH];   // 14400 B: [r*20+c][ch(72)]
    __shared__ float  sE[64 * 20];     // 5120 B: phase-1 partials / epilogue stage
    __shared__ float2 sP[16 * 9];      // 1152 B: per-pixel (ox,oy) per tap

    int t    = threadIdx.x;
    int lane = t & 63;
    int wv   = t >> 6;
    int b    = blockIdx.x & 7;          // image -> XCD pin
    int strip= blockIdx.x >> 3;         // 0..575
    int px0  = strip * 16;
    int i    = px0 / W_;                // whole strip on one row (96 % 16 == 0)
    int j0   = px0 - i * W_;
    int pxl  = lane & 15, kq = lane >> 4;
    int j    = j0 + pxl;
    const short* xb = x_t + (size_t)b * HW * 64;
    const short8 Z8 = {0,0,0,0,0,0,0,0};

    // ---- stage the 5x20 patch (clamped source; clamp-equivalent for sampling) ----
    for (int u = t; u < 800; u += 128) {
        int cb = u & 7, rc = u >> 3;         // rc = r*20+c, 0..99
        int r = rc / 20, c = rc - r * 20;
        int row = min(max(i - 2 + r, 0), H_ - 1);
        int col = min(max(j0 - 2 + c, 0), W_ - 1);
        *(short8*)&sX[rc * PCH + cb * 8] =
            *(const short8*)(xb + (row * W_ + col) * 64 + cb * 8);
    }
    __syncthreads();

    // ---- phase 1: offset conv from LDS patch. wave0: taps 0-4, wave1: 5-8 ----
    f32x4 pa0 = {0,0,0,0}, pa1 = {0,0,0,0};
    auto p1tap = [&](int n) {
        int di = n / 3 - 1, dj = n % 3 - 1;
        int ii = i + di, jj = j + dj;
        bool ok = (ii >= 0) & (ii < H_) & (jj >= 0) & (jj < W_);
        int rc = (di + 2) * 20 + (pxl + dj + 2);
#pragma unroll
        for (int q2 = 0; q2 < 2; ++q2) {
            short8 a = *(const short8*)&sX[rc * PCH + q2 * 32 + kq * 8];
            a = ok ? a : Z8;
            const short* wb = woff_frag + ((n * 2 + q2) * 2) * 512 + lane * 8;
            short8 b0 = *(const short8*)(wb);
            short8 b1 = *(const short8*)(wb + 512);
            pa0 = __builtin_amdgcn_mfma_f32_16x16x32_bf16(a, b0, pa0, 0, 0, 0);
            pa1 = __builtin_amdgcn_mfma_f32_16x16x32_bf16(a, b1, pa1, 0, 0, 0);
        }
    };
    if (wv == 0) {
#pragma unroll
        for (int q = 0; q < 5; ++q) p1tap(q);
    } else {
#pragma unroll
        for (int q = 0; q < 4; ++q) p1tap(5 + q);
    }
    {   // partials -> LDS: C/D col=lane&15 (=ch), row=(lane>>4)*4+r (=px)
        int col = lane & 15, rq = lane >> 4;
#pragma unroll
        for (int r = 0; r < 4; ++r)
            sE[(wv * 16 + rq * 4 + r) * 20 + col] = pa0[r];
        if (col < 2) {
#pragma unroll
            for (int r = 0; r < 4; ++r)
                sE[(wv * 16 + rq * 4 + r) * 20 + 16 + col] = pa1[r];
        }
    }
    __syncthreads();

    // ---- reduce partials + bias -> per-pixel offset pair table ----
#pragma unroll
    for (int s = 0; s < 2; ++s) {
        int idx = s * 128 + t;
        if (idx < 144) {
            int p = idx / 9, n = idx - p * 9;
            float ox = sE[p * 20 + n]     + sE[(16 + p) * 20 + n]     + b_off[n];
            float oy = sE[p * 20 + 9 + n] + sE[(16 + p) * 20 + 9 + n] + b_off[9 + n];
            sP[p * 9 + n] = make_float2(ox, oy);
        }
    }
    __syncthreads();

    // ---- phase 2: sample (LDS patch, global fallback) + GEMM. wv0: 0-3, wv1: 4-8 ----
    f32x4 acc[4];
#pragma unroll
    for (int nt = 0; nt < 4; ++nt) acc[nt] = (f32x4){0.f, 0.f, 0.f, 0.f};

    auto p2tap = [&](int n) {
        int di = n / 3 - 1, dj = n % 3 - 1;
        float2 o = sP[pxl * 9 + n];
        float fpx = (float)(i + di) + o.x;
        float fpy = (float)(j + dj) + o.y;
        float x0f = floorf(fpx), y0f = floorf(fpy);
        float lx = fpx - x0f, ly = fpy - y0f;
        int xi = (int)x0f, yi = (int)y0f;
        float wx0 = (xi >= 0  && xi <= H_ - 1) ? (1.0f - lx) : 0.0f;
        float wx1 = (xi >= -1 && xi <= H_ - 2) ? lx          : 0.0f;
        float wy0 = (yi >= 0  && yi <= W_ - 1) ? (1.0f - ly) : 0.0f;
        float wy1 = (yi >= -1 && yi <= W_ - 2) ? ly          : 0.0f;
        float w00 = wx0 * wy0, w10 = wx1 * wy0, w01 = wx0 * wy1, w11 = wx1 * wy1;
        int rp = xi - (i - 2), cp = yi - (j0 - 2);
        bool inp = (rp >= 0) & (rp <= 3) & (cp >= 0) & (cp <= 18);
        uint4v u[8];
        if (inp) {   // common path: patch reads (content is clamp-equivalent)
            int l00 = (rp * 20 + cp) * PCH;
            int l10 = l00 + 20 * PCH, l01 = l00 + PCH, l11 = l10 + PCH;
#pragma unroll
            for (int q2 = 0; q2 < 2; ++q2) {
                int cho = q2 * 32 + kq * 8;
                u[q2*4+0] = *(const uint4v*)&sX[l00 + cho];
                u[q2*4+1] = *(const uint4v*)&sX[l10 + cho];
                u[q2*4+2] = *(const uint4v*)&sX[l01 + cho];
                u[q2*4+3] = *(const uint4v*)&sX[l11 + cho];
            }
        }
        if (!inp) {  // rare: |offset| >= 1 -> direct global gather
            int r0 = min(max(xi,     0), H_ - 1) * W_;
            int r1 = min(max(xi + 1, 0), H_ - 1) * W_;
            int c0 = min(max(yi,     0), W_ - 1);
            int c1 = min(max(yi + 1, 0), W_ - 1);
#pragma unroll
            for (int q2 = 0; q2 < 2; ++q2) {
                int cho = q2 * 32 + kq * 8;
                u[q2*4+0] = *(const uint4v*)(xb + (r0 + c0) * 64 + cho);
                u[q2*4+1] = *(const uint4v*)(xb + (r1 + c0) * 64 + cho);
                u[q2*4+2] = *(const uint4v*)(xb + (r0 + c1) * 64 + cho);
                u[q2*4+3] = *(const uint4v*)(xb + (r1 + c1) * 64 + cho);
            }
        }
#pragma unroll
        for (int q2 = 0; q2 < 2; ++q2) {
            short8 A;
#pragma unroll
            for (int d = 0; d < 4; ++d) {
                float lo = w00 * bflo(u[q2*4+0][d]) + w10 * bflo(u[q2*4+1][d])
                         + w01 * bflo(u[q2*4+2][d]) + w11 * bflo(u[q2*4+3][d]);
                float hi = w00 * bfhi(u[q2*4+0][d]) + w10 * bfhi(u[q2*4+1][d])
                         + w01 * bfhi(u[q2*4+2][d]) + w11 * bfhi(u[q2*4+3][d]);
                A[2 * d]     = f2bf(lo);
                A[2 * d + 1] = f2bf(hi);
            }
            const short* wbp = wk_frag + ((n * 2 + q2) * 4) * 512 + lane * 8;
#pragma unroll
            for (int nt = 0; nt < 4; ++nt) {
                short8 bfr = *(const short8*)(wbp + nt * 512);
                acc[nt] = __builtin_amdgcn_mfma_f32_16x16x32_bf16(A, bfr, acc[nt], 0, 0, 0);
            }
        }
    };
    if (wv == 0) {
#pragma unroll
        for (int q = 0; q < 4; ++q) p2tap(q);
    } else {
#pragma unroll
        for (int q = 0; q < 5; ++q) p2tap(4 + q);
    }

    // ---- epilogue: cross-wave reduce in LDS, then coalesced stores ----
    __syncthreads();
    int col = lane & 15, rq = lane >> 4;
    if (wv == 0) {
#pragma unroll
        for (int nt = 0; nt < 4; ++nt) {
            int oc = nt * 16 + col;
            float bias = b_ker[oc];
#pragma unroll
            for (int r = 0; r < 4; ++r)
                sE[oc * 20 + rq * 4 + r] = acc[nt][r] + bias;
        }
    }
    __syncthreads();
    if (wv == 1) {
#pragma unroll
        for (int nt = 0; nt < 4; ++nt) {
            int oc = nt * 16 + col;
#pragma unroll
            for (int r = 0; r < 4; ++r)
                sE[oc * 20 + rq * 4 + r] += acc[nt][r];
        }
    }
    __syncthreads();

    int oc = t >> 1, half = t & 1;
    const float* se = &sE[oc * 20 + half * 8];
    float* outp = out + ((size_t)(b * OUTC + oc) * HW) + px0 + half * 8;
    *(f32x4*)outp       = *(const f32x4*)se;
    *(f32x4*)(outp + 4) = *(const f32x4*)(se + 4);
}

extern "C" void kernel_launch(void* const* d_in, const int* in_sizes, int n_in,
                              void* d_out, int out_size, void* d_ws, size_t ws_size,
                              hipStream_t stream) {
    const float* x     = (const float*)d_in[0];
    const float* w_off = (const float*)d_in[1];
    const float* b_off = (const float*)d_in[2];
    const float* w_ker = (const float*)d_in[3];
    const float* b_ker = (const float*)d_in[4];
    float* out = (float*)d_out;

    // workspace: x_t 9,437,184 B | wk_frag 73,728 B | woff_frag 36,864 B
    char*  wsb       = (char*)d_ws;
    short* x_t       = (short*)wsb;
    short* wk_frag   = (short*)(wsb + 9437184);
    short* woff_frag = wk_frag + 36864;

    prep_xpose  <<<1368, 256, 0, stream>>>(x, w_ker, w_off, x_t, wk_frag, woff_frag);
    deform_fused<<<4608, 128, 0, stream>>>(x_t, woff_frag, b_off, wk_frag, b_ker, out);
}